// Round 11
// baseline (622.566 us; speedup 1.0000x reference)
//
#include <hip/hip_runtime.h>
#include <hip/hip_bf16.h>

#define C 128
#define THREADS 256      // node/prep kernels: 4 waves/block
#define ETHREADS 128     // edge kernel: 2 waves/block
#define EWPB 2           // edge waves per block
#define TILE 64          // node rows per block
#define EPW 16           // edges per wave-tile
#define GTILES 8         // tiles per wave, steady-state loop (NOT unrolled)
#define RCAP 10          // LDS ring entries per wave (run partials)
#define LDSPAD 8
#define LDSW (C + LDSPAD)    // 136 ushorts/row
#define LOG2E 1.44269504088896340736f

typedef unsigned short ushortT;
typedef __attribute__((ext_vector_type(8))) short short8;
typedef __attribute__((ext_vector_type(8))) ushortT ushort8;
typedef __attribute__((ext_vector_type(4))) float floatx4;
typedef __attribute__((ext_vector_type(4))) unsigned uintx4;

// ---- bf16 helpers ----
__device__ __forceinline__ unsigned pk2(float a, float b) {     // float2 -> 2x bf16 (RNE, 1 inst)
    float2 f; f.x = a; f.y = b;
    union { unsigned u; __hip_bfloat162 h; } cv; cv.h = __float22bfloat162_rn(f);
    return cv.u;
}
__device__ __forceinline__ ushortT f2bf(float x) {              // HW RNE via cvt_pk
    return (ushortT)(pk2(x, x) & 0xffffu);
}
__device__ __forceinline__ float bf2f(ushortT h) {
    union { unsigned u; float f; } v; v.u = ((unsigned)h) << 16;
    return v.f;
}
__device__ __forceinline__ float2 upk2(unsigned u) {            // 2x bf16 -> float2
    union { unsigned u; __hip_bfloat162 h; } cv; cv.u = u;
    return __bfloat1622float2(cv.h);
}
__device__ __forceinline__ float exp2_hw(float x) {             // 2^x, single v_exp_f32
    float r; asm("v_exp_f32 %0, %1" : "=v"(r) : "v"(x)); return r;
}
__device__ __forceinline__ void atomic_add_f32(float* p, float v) {
    __hip_atomic_fetch_add(p, v, __ATOMIC_RELAXED, __HIP_MEMORY_SCOPE_AGENT);
}

// ============================================================================
// MFMA helpers (zero-init acc, bias in epilogue — round-2-proven codegen)
// ============================================================================
__device__ __forceinline__ void wave_gemm(const ushortT (*A)[LDSW],
                                          const ushortT* __restrict__ Bp,
                                          int quad, int m16, int lane,
                                          floatx4 acc[8])
{
#pragma unroll
    for (int nt = 0; nt < 8; ++nt) { acc[nt][0]=0.f; acc[nt][1]=0.f; acc[nt][2]=0.f; acc[nt][3]=0.f; }
#pragma unroll 1
    for (int ks = 0; ks < 4; ++ks) {
        const short8 af = *(const short8*)&A[m16][ks * 32 + quad * 8];
        const ushortT* bpk = Bp + (size_t)ks * 4096 + (size_t)lane * 8;
#pragma unroll
        for (int nt = 0; nt < 8; ++nt) {
            const short8 bf = *(const short8*)(bpk + nt * 512);
            acc[nt] = __builtin_amdgcn_mfma_f32_16x16x32_bf16(af, bf, acc[nt], 0, 0, 0);
        }
    }
}

__device__ __forceinline__ void cstore_relu_r(ushortT (*A)[LDSW], floatx4 acc[8],
                                              const float bias[8], int quad, int m16)
{
#pragma unroll
    for (int nt = 0; nt < 8; ++nt) {
        const float b = bias[nt];
#pragma unroll
        for (int r = 0; r < 4; r += 2) {
            const unsigned p = pk2(fmaxf(acc[nt][r] + b, 0.f), fmaxf(acc[nt][r + 1] + b, 0.f));
            A[quad * 4 + r][nt * 16 + m16]     = (ushortT)(p & 0xffffu);
            A[quad * 4 + r + 1][nt * 16 + m16] = (ushortT)(p >> 16);
        }
    }
}

// pack one matrix entry into MFMA B-fragment order
__device__ __forceinline__ ushortT pack_one(const float* __restrict__ W, int u) {
    const int j = u & 7, lane = (u >> 3) & 63, f = u >> 9;  // u in [0,16384)
    const int nt = f & 7, ks = f >> 3;
    const int n = nt * 16 + (lane & 15);
    const int k = ks * 32 + (lane >> 4) * 8 + j;
    return f2bf(W[k * C + n]);
}

// ============================================================================
// prep1 (fused): pack Bpack (edge MLP, aw2 pre-scaled by log2e),
// pack Bpack2 (Wdst,Wsrc,Wlin,Win), pack BpackO (W_out),
// cvt pos->bf16 (float4 vectorized), hist of dst degrees. Block-role ranges.
// ============================================================================
extern "C" __global__ void __launch_bounds__(256)
prep1(const float* __restrict__ pw1, const float* __restrict__ pw2,
      const float* __restrict__ aw1, const float* __restrict__ aw2,
      const float* __restrict__ Wd,  const float* __restrict__ Wsrc,
      const float* __restrict__ Wl,  const float* __restrict__ Win,
      const float* __restrict__ Wout,
      const float* __restrict__ pos, ushortT* __restrict__ pos_bf,
      const int* __restrict__ ei, int* __restrict__ deg,
      ushortT* __restrict__ Bpack, ushortT* __restrict__ Bpack2,
      ushortT* __restrict__ BpackO, int N, int E)
{
    const int nb_cvt = (N * 32 + 255) / 256;
    const int b = blockIdx.x, tid = threadIdx.x;
    if (b < 256) {
        const int t = b * 256 + tid;
        const int s = t >> 14;
        const float* W = (s == 0) ? pw1 : (s == 1) ? pw2 : (s == 2) ? aw1 : aw2;
        const int u = t & 16383;
        const int j = u & 7, lane = (u >> 3) & 63, f = u >> 9;
        const int nt = f & 7, ks = f >> 3;
        const int n = nt * 16 + (lane & 15);
        const int k = ks * 32 + (lane >> 4) * 8 + j;
        float v = W[k * C + n];
        if (s == 3) v *= LOG2E;          // exp2 fold: attn layer-2 in log2 domain
        Bpack[t] = f2bf(v);
    } else if (b < 512) {
        const int t = (b - 256) * 256 + tid;
        const int s = t >> 14;
        const float* W = (s == 0) ? Wd : (s == 1) ? Wsrc : (s == 2) ? Wl : Win;
        Bpack2[t] = pack_one(W, t & 16383);
    } else if (b < 576) {
        const int t = (b - 512) * 256 + tid;     // [0, 16384)
        BpackO[t] = pack_one(Wout, t);
    } else if (b < 576 + nb_cvt) {
        const int i = (b - 576) * 256 + tid;
        if (i < N * 32) {
            const float4 v = ((const float4*)pos)[i];
            uint2 o; o.x = pk2(v.x, v.y); o.y = pk2(v.z, v.w);
            ((uint2*)pos_bf)[i] = o;
        }
    } else {
        const int e = (b - 576 - nb_cvt) * 256 + tid;
        if (e < E) atomicAdd(&deg[ei[E + e]], 1);
    }
}

extern "C" __global__ void __launch_bounds__(1024)
k_scan(const int* __restrict__ deg, int* __restrict__ off, int n)
{
    __shared__ int part[1024];
    const int t = threadIdx.x;
    const int chunk = (((n + 1023) / 1024) + 3) & ~3;      // multiple of 4
    const int lo = t * chunk, hi = min(lo + chunk, n);      // n%4==0 -> hi-lo %4==0
    int s = 0;
    for (int i = lo; i < hi; i += 4) {
        const int4 d4 = *(const int4*)(deg + i);
        s += d4.x + d4.y + d4.z + d4.w;
    }
    part[t] = s;
    __syncthreads();
    for (int d = 1; d < 1024; d <<= 1) {
        int v = (t >= d) ? part[t - d] : 0;
        __syncthreads();
        part[t] += v;
        __syncthreads();
    }
    int run = (t == 0) ? 0 : part[t - 1];
    for (int i = lo; i < hi; i += 4) {
        const int4 d4 = *(const int4*)(deg + i);
        int4 o;
        o.x = run;
        o.y = o.x + d4.x;
        o.z = o.y + d4.y;
        o.w = o.z + d4.z;
        *(int4*)(off + i) = o;
        run = o.w + d4.w;
    }
}

// ============================================================================
// prep2 (fused): node role (all-MFMA qkv + P = pos@pw1 hoist) + scatter role.
// ============================================================================
extern "C" __global__ void __launch_bounds__(256)
prep2(const float* __restrict__ x, const float* __restrict__ b_in,
      const ushortT* __restrict__ Bp2, const ushortT* __restrict__ Bpk,
      const float* __restrict__ pb1, const ushortT* __restrict__ pos_bf,
      ushortT* __restrict__ q_bf, ushortT* __restrict__ k_bf, ushortT* __restrict__ v_bf,
      ushortT* __restrict__ Pd_arr, ushortT* __restrict__ Ps_arr,
      const int* __restrict__ ei, const int* __restrict__ offp, int* __restrict__ curp,
      int* __restrict__ ss, int* __restrict__ sd, int N, int E, int nb_node)
{
    __shared__ ushortT xs[TILE][LDSW];   // 17.4 KB (ostage overlays this)
    __shared__ ushortT hs[TILE][LDSW];   // 17.4 KB
    const int b = blockIdx.x, tx = threadIdx.x;

    if (b >= nb_node) {
        // ---- scatter role ----
        const int e = (b - nb_node) * 256 + tx;
        if (e < E) {
            const int d = ei[E + e];
            const int p = offp[d] + atomicAdd(&curp[d], 1);
            ss[p] = ei[e];
            sd[p] = d;
        }
        return;
    }

    // ---- node role ----
    const int rg = tx >> 5;
    const int oc0 = (tx & 31) << 2;
    const int row0 = b * TILE;

    // stage x -> bf16 (wave-private rows)
#pragma unroll
    for (int j = 0; j < 8; ++j) {
        const int r = rg * 8 + j, n = row0 + r;
        float4 xv; xv.x = xv.y = xv.z = xv.w = 0.f;
        if (n < N) xv = *(const float4*)(x + (size_t)n * C + oc0);
        *(unsigned*)&xs[r][oc0]     = pk2(xv.x, xv.y);
        *(unsigned*)&xs[r][oc0 + 2] = pk2(xv.z, xv.w);
    }

    const int wv = tx >> 6, lane = tx & 63;
    const int quad = lane >> 4, m16 = lane & 15;
    const int row = lane >> 2, li = lane & 3;

    float binv[8];
#pragma unroll
    for (int nt = 0; nt < 8; ++nt) binv[nt] = b_in[nt * 16 + m16];

    const ushortT (*Ax)[LDSW] = (const ushortT (*)[LDSW])&xs[wv * 16];
    ushortT (*Ah)[LDSW] = (ushortT (*)[LDSW])&hs[wv * 16];

    floatx4 macc[8];
    // h = relu(x @ W_in + b_in)   (W_in in Bpack2 slot 3)
    wave_gemm(Ax, Bp2 + (size_t)3 * 16384, quad, m16, lane, macc);
    cstore_relu_r(Ah, macc, binv, quad, m16);

    __syncthreads();   // all xs reads done before ostage overlay is written

    ushortT (*OS)[LDSW] = (ushortT (*)[LDSW])&xs[wv * 16];   // ostage overlay
    ushortT* outs[3];
    outs[0] = q_bf; outs[1] = k_bf; outs[2] = v_bf;

    const int nrow = row0 + wv * 16 + row;

#pragma unroll 1
    for (int m = 0; m < 3; ++m) {
        wave_gemm((const ushortT (*)[LDSW])Ah, Bp2 + (size_t)m * 16384, quad, m16, lane, macc);
#pragma unroll
        for (int nt = 0; nt < 8; ++nt) {
#pragma unroll
            for (int r = 0; r < 4; r += 2) {
                const unsigned p = pk2(macc[nt][r], macc[nt][r + 1]);
                OS[quad * 4 + r][nt * 16 + m16]     = (ushortT)(p & 0xffffu);
                OS[quad * 4 + r + 1][nt * 16 + m16] = (ushortT)(p >> 16);
            }
        }
        if (nrow < N) {
#pragma unroll
            for (int i = 0; i < 4; ++i) {
                const ushort8 v8 = *(const ushort8*)&OS[row][i * 32 + li * 8];
                *(ushort8*)(outs[m] + (size_t)nrow * C + i * 32 + li * 8) = v8;
            }
        }
    }

    // ---- P = pos @ pw1 (hoisted pos_nn layer-1 GEMM) ----
    __syncthreads();   // hs reads (gemms) + OS reads (stores) all complete
    {
        const ushortT* srcp = pos_bf + (size_t)min(nrow, N - 1) * C;
#pragma unroll
        for (int i = 0; i < 4; ++i) {
            const ushort8 v8 = *(const ushort8*)(srcp + i * 32 + li * 8);
            *(ushort8*)&hs[wv * 16 + row][i * 32 + li * 8] = v8;
        }
    }
    __syncthreads();
    wave_gemm((const ushortT (*)[LDSW])Ah, Bpk /*slot 0 = pw1*/, quad, m16, lane, macc);

    float b1v[8];
#pragma unroll
    for (int nt = 0; nt < 8; ++nt) b1v[nt] = pb1[nt * 16 + m16];

    // pass 1: Pd = P + b1
#pragma unroll
    for (int nt = 0; nt < 8; ++nt) {
#pragma unroll
        for (int r = 0; r < 4; r += 2) {
            const unsigned p = pk2(macc[nt][r] + b1v[nt], macc[nt][r + 1] + b1v[nt]);
            OS[quad * 4 + r][nt * 16 + m16]     = (ushortT)(p & 0xffffu);
            OS[quad * 4 + r + 1][nt * 16 + m16] = (ushortT)(p >> 16);
        }
    }
    if (nrow < N) {
#pragma unroll
        for (int i = 0; i < 4; ++i) {
            const ushort8 v8 = *(const ushort8*)&OS[row][i * 32 + li * 8];
            *(ushort8*)(Pd_arr + (size_t)nrow * C + i * 32 + li * 8) = v8;
        }
    }
    __syncthreads();
    // pass 2: Ps = P
#pragma unroll
    for (int nt = 0; nt < 8; ++nt) {
#pragma unroll
        for (int r = 0; r < 4; r += 2) {
            const unsigned p = pk2(macc[nt][r], macc[nt][r + 1]);
            OS[quad * 4 + r][nt * 16 + m16]     = (ushortT)(p & 0xffffu);
            OS[quad * 4 + r + 1][nt * 16 + m16] = (ushortT)(p >> 16);
        }
    }
    if (nrow < N) {
#pragma unroll
        for (int i = 0; i < 4; ++i) {
            const ushort8 v8 = *(const ushort8*)&OS[row][i * 32 + li * 8];
            *(ushort8*)(Ps_arr + (size_t)nrow * C + i * 32 + li * 8) = v8;
        }
    }
}

// ============================================================================
// kernel 2 (MFMA): edges SORTED BY DST; segmented-scan epilogue.
// This round: run flushes go to a per-wave LDS RING (RCAP entries); all
// atomics deferred to one end-of-wave drain -> in-loop vmcnt queue holds only
// gathers/index loads (counted waits, no fabric-atomic RTT on critical path).
// Overflow (runs > RCAP, rare) falls back to an immediate atomic flush.
// ============================================================================
__device__ __forceinline__ void gather4(const ushortT* __restrict__ base, int node, int li,
                                        ushort8 dst[4])
{
    const ushort8* p = (const ushort8*)(base + (size_t)node * C) + li;
    dst[0] = p[0]; dst[1] = p[4]; dst[2] = p[8]; dst[3] = p[12];   // chunk i at ushort8 index i*4+li
}

extern "C" __global__ void __launch_bounds__(ETHREADS)
edge_mfma(const ushortT* __restrict__ Pd_arr, const ushortT* __restrict__ Ps_arr,
          const int* __restrict__ ss, const int* __restrict__ sd,
          const ushortT* __restrict__ q_bf, const ushortT* __restrict__ k_bf,
          const ushortT* __restrict__ v_bf, const ushortT* __restrict__ Bpack,
          const float* __restrict__ pb2,
          const float* __restrict__ ab1, const float* __restrict__ ab2,
          float* __restrict__ z, float* __restrict__ aggU, int E)
{
    __shared__ ushortT Aslab[EWPB][EPW][LDSW];            // 8.7 KB
    __shared__ ushortT Vslab[EWPB][EPW][LDSW];            // 8.7 KB
    __shared__ int     Dslab[EWPB][EPW];                  // 128 B
    __shared__ __align__(16) float Ring[EWPB][RCAP][2][C];// 20.5 KB ([0]=z, [1]=g)
    __shared__ int     RingDst[EWPB][RCAP];               // 80 B
    const int tid = threadIdx.x;
    const int wv = tid >> 6, lane = tid & 63;
    const int quad = lane >> 4, m16 = lane & 15;
    const int row = lane >> 2, li = lane & 3;      // line-coherent staging mapping
    ushortT (*A)[LDSW] = Aslab[wv];
    ushortT (*V)[LDSW] = Vslab[wv];

    float pb2v[8], ab1v[8], ab2v[8];
#pragma unroll
    for (int nt = 0; nt < 8; ++nt) {
        pb2v[nt] = pb2[nt * 16 + m16];
        ab1v[nt] = ab1[nt * 16 + m16];
        ab2v[nt] = ab2[nt * 16 + m16] * LOG2E;     // log2-domain bias
    }

    const ushortT* B1 = Bpack + 16384;
    const ushortT* B2 = Bpack + 32768;
    const ushortT* B3 = Bpack + 49152;

    const int wave_base = (blockIdx.x * EWPB + wv) * (GTILES * EPW);

    const int c2 = lane * 2;
    int   cur_dst = -1;
    int   ring_cnt = 0;
    float zs0 = 0.f, zs1 = 0.f, gs0 = 0.f, gs1 = 0.f;

    // ---- prologue: indices for tile 0 ----
    int es, ed, sdr[4];
    {
        const int eidx = min(wave_base + row, E - 1);
        es = ss[eidx]; ed = sd[eidx];
#pragma unroll
        for (int r = 0; r < 4; ++r)
            sdr[r] = sd[min(wave_base + quad * 4 + r, E - 1)];
    }

#pragma unroll 1
    for (int t = 0; t < GTILES; ++t) {
        const int e_base = wave_base + t * EPW;
        if (m16 == 0) {
#pragma unroll
            for (int r = 0; r < 4; ++r) Dslab[wv][quad * 4 + r] = sdr[r];
        }

        ushort8 Pd[4], Ps[4], Qv[4], Kv[4], Vv[4];
        gather4(Pd_arr, ed, li, Pd); gather4(Ps_arr, es, li, Ps);
        gather4(q_bf,  ed, li, Qv); gather4(k_bf,  es, li, Kv);
        gather4(v_bf,  es, li, Vv);

        // ---- A1 = relu(Pd[dst] - Ps[src])  (pos_nn layer 1, hoisted GEMM);
        //      stage v into Vslab ----
#pragma unroll
        for (int i = 0; i < 4; ++i) {
            const uintx4 pd = *(const uintx4*)&Pd[i];
            const uintx4 ps = *(const uintx4*)&Ps[i];
            uintx4 o;
#pragma unroll
            for (int w = 0; w < 4; ++w) {
                const float2 a = upk2(pd[w]), b = upk2(ps[w]);
                o[w] = pk2(fmaxf(a.x - b.x, 0.f), fmaxf(a.y - b.y, 0.f));
            }
            *(uintx4*)&A[row][i * 32 + li * 8] = o;
            *(ushort8*)&V[row][i * 32 + li * 8] = Vv[i];
        }

        floatx4 acc[8];

        // ---- pos_nn layer 2 -> delta (packed regs + slab) ----
        wave_gemm(A, B1, quad, m16, lane, acc);
        unsigned dlp[8][2];
#pragma unroll
        for (int nt = 0; nt < 8; ++nt) {
            const float b = pb2v[nt];
            const unsigned p0 = pk2(fmaxf(acc[nt][0] + b, 0.f), fmaxf(acc[nt][1] + b, 0.f));
            const unsigned p1 = pk2(fmaxf(acc[nt][2] + b, 0.f), fmaxf(acc[nt][3] + b, 0.f));
            dlp[nt][0] = p0; dlp[nt][1] = p1;
            A[quad * 4 + 0][nt * 16 + m16] = (ushortT)(p0 & 0xffffu);
            A[quad * 4 + 1][nt * 16 + m16] = (ushortT)(p0 >> 16);
            A[quad * 4 + 2][nt * 16 + m16] = (ushortT)(p1 & 0xffffu);
            A[quad * 4 + 3][nt * 16 + m16] = (ushortT)(p1 >> 16);
        }

        // ---- A2 = bf16( q[dst] - k[src] + delta ) ----
#pragma unroll
        for (int i = 0; i < 4; ++i) {
            const uintx4 dv = *(const uintx4*)&A[row][i * 32 + li * 8];
            const uintx4 qv = *(const uintx4*)&Qv[i];
            const uintx4 kv = *(const uintx4*)&Kv[i];
            uintx4 o;
#pragma unroll
            for (int w = 0; w < 4; ++w) {
                const float2 qq = upk2(qv[w]), kk = upk2(kv[w]), dd = upk2(dv[w]);
                o[w] = pk2(qq.x - kk.x + dd.x, qq.y - kk.y + dd.y);
            }
            *(uintx4*)&A[row][i * 32 + li * 8] = o;
        }

        // ---- prefetch next tile's indices (hides under attn MFMAs + scan) ----
        int nes = es, ned = ed, nsdr[4];
#pragma unroll
        for (int r = 0; r < 4; ++r) nsdr[r] = sdr[r];
        if (t + 1 < GTILES) {
            const int e2 = e_base + EPW;
            const int ei2 = min(e2 + row, E - 1);
            nes = ss[ei2]; ned = sd[ei2];
#pragma unroll
            for (int r = 0; r < 4; ++r)
                nsdr[r] = sd[min(e2 + quad * 4 + r, E - 1)];
        }

        // ---- attn_nn layer 1 ----
        wave_gemm(A, B2, quad, m16, lane, acc);
        cstore_relu_r(A, acc, ab1v, quad, m16);

        // ---- attn_nn layer 2 (log2 domain) -> ea = exp2(relu(alpha'+b')) ----
        wave_gemm(A, B3, quad, m16, lane, acc);
#pragma unroll
        for (int nt = 0; nt < 8; ++nt) {
            const float b = ab2v[nt];
#pragma unroll
            for (int r = 0; r < 4; ++r)
                acc[nt][r] = exp2_hw(fmaxf(acc[nt][r] + b, 0.f));  // == exp(relu(alpha))
        }

        // ---- zero ea for out-of-range (clamped duplicate) edges ----
        if (e_base + EPW > E) {
#pragma unroll
            for (int r = 0; r < 4; ++r)
                if (e_base + quad * 4 + r >= E) {
#pragma unroll
                    for (int nt = 0; nt < 8; ++nt) acc[nt][r] = 0.f;
                }
        }

        // ---- transpose: A <- ea (bf16), V <- v+delta (bf16), edge-major ----
#pragma unroll
        for (int nt = 0; nt < 8; ++nt) {
#pragma unroll
            for (int r = 0; r < 4; ++r) {
                const float2 dpair = upk2(dlp[nt][r >> 1]);
                const float dlv = (r & 1) ? dpair.y : dpair.x;
                const int ridx = quad * 4 + r, cidx = nt * 16 + m16;
                const float vv = bf2f(V[ridx][cidx]);
                V[ridx][cidx] = f2bf(vv + dlv);
                A[ridx][cidx] = f2bf(acc[nt][r]);
            }
        }

        // ---- per-lane segmented scan; run flushes -> LDS ring (no atomics) ----
#pragma unroll 4
        for (int e = 0; e < EPW; ++e) {
            const int d = Dslab[wv][e];
            const float2 ea2 = upk2(*(const unsigned*)&A[e][c2]);
            const float2 vp2 = upk2(*(const unsigned*)&V[e][c2]);
            if (d != cur_dst) {
                if (cur_dst >= 0) {
                    if (ring_cnt < RCAP) {
                        RingDst[wv][ring_cnt] = cur_dst;   // uniform value, same-addr write
                        float2 zz; zz.x = zs0; zz.y = zs1;
                        float2 gg; gg.x = gs0; gg.y = gs1;
                        *(float2*)&Ring[wv][ring_cnt][0][c2] = zz;
                        *(float2*)&Ring[wv][ring_cnt][1][c2] = gg;
                        ++ring_cnt;
                    } else {                               // overflow (rare): direct atomics
                        float* zp = z    + (size_t)cur_dst * C + c2;
                        float* gp = aggU + (size_t)cur_dst * C + c2;
                        atomic_add_f32(zp,     zs0);
                        atomic_add_f32(zp + 1, zs1);
                        atomic_add_f32(gp,     gs0);
                        atomic_add_f32(gp + 1, gs1);
                    }
                }
                cur_dst = d;
                zs0 = ea2.x;           zs1 = ea2.y;
                gs0 = ea2.x * vp2.x;   gs1 = ea2.y * vp2.y;
            } else {
                zs0 += ea2.x;                   zs1 += ea2.y;
                gs0 = fmaf(ea2.x, vp2.x, gs0);  gs1 = fmaf(ea2.y, vp2.y, gs1);
            }
        }

        // rotate prefetched indices
        es = nes; ed = ned;
#pragma unroll
        for (int r = 0; r < 4; ++r) sdr[r] = nsdr[r];
    }

    // ---- end-of-wave drain: carry + ring entries -> atomics (once) ----
    if (cur_dst >= 0) {
        float* zp = z    + (size_t)cur_dst * C + c2;
        float* gp = aggU + (size_t)cur_dst * C + c2;
        atomic_add_f32(zp,     zs0);
        atomic_add_f32(zp + 1, zs1);
        atomic_add_f32(gp,     gs0);
        atomic_add_f32(gp + 1, gs1);
    }
#pragma unroll 1
    for (int i = 0; i < ring_cnt; ++i) {
        const int d = RingDst[wv][i];
        const float2 zz = *(const float2*)&Ring[wv][i][0][c2];
        const float2 gg = *(const float2*)&Ring[wv][i][1][c2];
        float* zp = z    + (size_t)d * C + c2;
        float* gp = aggU + (size_t)d * C + c2;
        atomic_add_f32(zp,     zz.x);
        atomic_add_f32(zp + 1, zz.y);
        atomic_add_f32(gp,     gg.x);
        atomic_add_f32(gp + 1, gg.y);
    }
}

// ============================================================================
// kernel 3 (MFMA): out = relu( bf16(aggU/(z+1e-16)) @ W_out + b_out )
// ============================================================================
extern "C" __global__ void __launch_bounds__(THREADS)
out_kernel(const float* __restrict__ aggU, const float* __restrict__ z,
           const ushortT* __restrict__ BpO, const float* __restrict__ b_out,
           float* __restrict__ out, int N)
{
    __shared__ ushortT us[TILE][LDSW];   // 17.4 KB
    const int tx = threadIdx.x;
    const int rg = tx >> 5;
    const int oc0 = (tx & 31) << 2;
    const int row0 = blockIdx.x * TILE;

#pragma unroll
    for (int j = 0; j < 8; ++j) {
        const int r = rg * 8 + j, n = row0 + r;
        float4 a; a.x = a.y = a.z = a.w = 0.f;
        if (n < N) {
            const float4 g  = *(const float4*)(aggU + (size_t)n * C + oc0);
            const float4 zz = *(const float4*)(z    + (size_t)n * C + oc0);
            a.x = g.x / (zz.x + 1e-16f);
            a.y = g.y / (zz.y + 1e-16f);
            a.z = g.z / (zz.z + 1e-16f);
            a.w = g.w / (zz.w + 1e-16f);
        }
        *(unsigned*)&us[r][oc0]     = pk2(a.x, a.y);
        *(unsigned*)&us[r][oc0 + 2] = pk2(a.z, a.w);
    }
    // rows rg*8+j are wave-private (rg in {2wv,2wv+1}) -> no barrier

    const int wv = tx >> 6, lane = tx & 63;
    const int quad = lane >> 4, m16 = lane & 15;

    floatx4 macc[8];
    wave_gemm((const ushortT (*)[LDSW])&us[wv * 16], BpO, quad, m16, lane, macc);

    float bo[8];
#pragma unroll
    for (int nt = 0; nt < 8; ++nt) bo[nt] = b_out[nt * 16 + m16];

#pragma unroll
    for (int r = 0; r < 4; ++r) {
        const int n = row0 + wv * 16 + quad * 4 + r;
        if (n < N) {
            float* op = out + (size_t)n * C + m16;
#pragma unroll
            for (int nt = 0; nt < 8; ++nt)
                op[nt * 16] = fmaxf(macc[nt][r] + bo[nt], 0.f);
        }
    }
}

// ---------------------------------------------------------------------------
extern "C" void kernel_launch(void* const* d_in, const int* in_sizes, int n_in,
                              void* d_out, int out_size, void* d_ws, size_t ws_size,
                              hipStream_t stream)
{
    const float* x     = (const float*)d_in[0];
    const float* pos   = (const float*)d_in[1];
    const int*   ei    = (const int*)  d_in[2];
    const float* W_in  = (const float*)d_in[3];
    const float* b_in  = (const float*)d_in[4];
    const float* W_lin = (const float*)d_in[5];
    const float* W_src = (const float*)d_in[6];
    const float* W_dst = (const float*)d_in[7];
    const float* pw1   = (const float*)d_in[8];
    const float* pb1   = (const float*)d_in[9];
    const float* pw2   = (const float*)d_in[10];
    const float* pb2   = (const float*)d_in[11];
    const float* aw1   = (const float*)d_in[12];
    const float* ab1   = (const float*)d_in[13];
    const float* aw2   = (const float*)d_in[14];
    const float* ab2   = (const float*)d_in[15];
    const float* W_out = (const float*)d_in[16];
    const float* b_out = (const float*)d_in[17];

    const int N = in_sizes[0] / C;
    const int E = in_sizes[2] / 2;
    const size_t NC = (size_t)N * C;

    // workspace layout — ALL gathered bf16 arrays 256-B aligned:
    //   z | aggU | q | k | v | Pd | Ps | pos_bf | Bpack | Bpack2 | BpackO |
    //   deg | cur | off | ss | sd
    float*   z      = (float*)d_ws;                          // [N,C] fp32
    float*   aggU   = z + NC;                                // [N,C] fp32
    ushortT* q_bf   = (ushortT*)(aggU + NC);                 // [N,C] bf16 (256B-aligned)
    ushortT* k_bf   = q_bf + NC;
    ushortT* v_bf   = k_bf + NC;
    ushortT* Pd_arr = v_bf + NC;                             // [N,C] bf16: pos@pw1 + pb1
    ushortT* Ps_arr = Pd_arr + NC;                           // [N,C] bf16: pos@pw1
    ushortT* pos_bf = Ps_arr + NC;
    ushortT* Bpack  = pos_bf + NC;                           // 65536 bf16 (edge MLP weights)
    ushortT* Bpack2 = Bpack + 65536;                         // 65536 bf16 (Wdst,Wsrc,Wlin,Win)
    ushortT* BpackO = Bpack2 + 65536;                        // 16384 bf16 (W_out)
    int*     deg    = (int*)(BpackO + 16384);                // [N]
    int*     curp   = deg + N;                               // [N]
    int*     offp   = curp + N;                              // [N]
    int*     ss     = offp + N;                              // [E] sorted src
    int*     sdst   = ss + E;                                // [E] sorted dst

    hipMemsetAsync(z, 0, 2 * NC * sizeof(float), stream);
    hipMemsetAsync(deg, 0, 2 * (size_t)N * sizeof(int), stream);  // deg + cur

    const int nb_cvt  = (N * 32 + 255) / 256;
    const int nb_hist = (E + 255) / 256;
    prep1<<<576 + nb_cvt + nb_hist, 256, 0, stream>>>(pw1, pw2, aw1, aw2,
                                                      W_dst, W_src, W_lin, W_in, W_out,
                                                      pos, pos_bf, ei, deg,
                                                      Bpack, Bpack2, BpackO, N, E);

    k_scan<<<1, 1024, 0, stream>>>(deg, offp, N);

    const int nb = (N + TILE - 1) / TILE;
    prep2<<<nb + nb_hist, 256, 0, stream>>>(x, b_in, Bpack2, Bpack, pb1, pos_bf,
                                            q_bf, k_bf, v_bf, Pd_arr, Ps_arr,
                                            ei, offp, curp, ss, sdst, N, E, nb);

    const int edges_per_block = EWPB * GTILES * EPW;         // 256
    const int eb = (E + edges_per_block - 1) / edges_per_block;
    edge_mfma<<<eb, ETHREADS, 0, stream>>>(Pd_arr, Ps_arr, ss, sdst, q_bf, k_bf, v_bf, Bpack,
                                           pb2, ab1, ab2, z, aggU, E);
    out_kernel<<<nb, THREADS, 0, stream>>>(aggU, z, BpackO, b_out, (float*)d_out, N);
}

// Round 12
// 602.796 us; speedup vs baseline: 1.0328x; 1.0328x over previous
//
#include <hip/hip_runtime.h>
#include <hip/hip_bf16.h>

#define C 128
#define THREADS 256      // node/prep kernels: 4 waves/block
#define ETHREADS 128     // edge kernel: 2 waves/block
#define EWPB 2           // edge waves per block
#define TILE 64          // node rows per block
#define EPW 16           // edges per wave-tile
#define GTILES 8         // tiles per wave, steady-state loop (NOT unrolled)
#define LDSPAD 8
#define LDSW (C + LDSPAD)    // 136 ushorts/row
#define LOG2E 1.44269504088896340736f

typedef unsigned short ushortT;
typedef __attribute__((ext_vector_type(8))) short short8;
typedef __attribute__((ext_vector_type(8))) ushortT ushort8;
typedef __attribute__((ext_vector_type(4))) float floatx4;
typedef __attribute__((ext_vector_type(4))) unsigned uintx4;

// ---- bf16 helpers ----
__device__ __forceinline__ unsigned pk2(float a, float b) {     // float2 -> 2x bf16 (RNE, 1 inst)
    float2 f; f.x = a; f.y = b;
    union { unsigned u; __hip_bfloat162 h; } cv; cv.h = __float22bfloat162_rn(f);
    return cv.u;
}
__device__ __forceinline__ ushortT f2bf(float x) {              // HW RNE via cvt_pk
    return (ushortT)(pk2(x, x) & 0xffffu);
}
__device__ __forceinline__ float bf2f(ushortT h) {
    union { unsigned u; float f; } v; v.u = ((unsigned)h) << 16;
    return v.f;
}
__device__ __forceinline__ float2 upk2(unsigned u) {            // 2x bf16 -> float2
    union { unsigned u; __hip_bfloat162 h; } cv; cv.u = u;
    return __bfloat1622float2(cv.h);
}
__device__ __forceinline__ float exp2_hw(float x) {             // 2^x, single v_exp_f32
    float r; asm("v_exp_f32 %0, %1" : "=v"(r) : "v"(x)); return r;
}
__device__ __forceinline__ void atomic_add_f32(float* p, float v) {
    __hip_atomic_fetch_add(p, v, __ATOMIC_RELAXED, __HIP_MEMORY_SCOPE_AGENT);
}

// ============================================================================
// MFMA helpers (zero-init acc, bias in epilogue — round-2-proven codegen)
// ============================================================================
__device__ __forceinline__ void wave_gemm(const ushortT (*A)[LDSW],
                                          const ushortT* __restrict__ Bp,
                                          int quad, int m16, int lane,
                                          floatx4 acc[8])
{
#pragma unroll
    for (int nt = 0; nt < 8; ++nt) { acc[nt][0]=0.f; acc[nt][1]=0.f; acc[nt][2]=0.f; acc[nt][3]=0.f; }
#pragma unroll 1
    for (int ks = 0; ks < 4; ++ks) {
        const short8 af = *(const short8*)&A[m16][ks * 32 + quad * 8];
        const ushortT* bpk = Bp + (size_t)ks * 4096 + (size_t)lane * 8;
#pragma unroll
        for (int nt = 0; nt < 8; ++nt) {
            const short8 bf = *(const short8*)(bpk + nt * 512);
            acc[nt] = __builtin_amdgcn_mfma_f32_16x16x32_bf16(af, bf, acc[nt], 0, 0, 0);
        }
    }
}

__device__ __forceinline__ void cstore_relu_r(ushortT (*A)[LDSW], floatx4 acc[8],
                                              const float bias[8], int quad, int m16)
{
#pragma unroll
    for (int nt = 0; nt < 8; ++nt) {
        const float b = bias[nt];
#pragma unroll
        for (int r = 0; r < 4; r += 2) {
            const unsigned p = pk2(fmaxf(acc[nt][r] + b, 0.f), fmaxf(acc[nt][r + 1] + b, 0.f));
            A[quad * 4 + r][nt * 16 + m16]     = (ushortT)(p & 0xffffu);
            A[quad * 4 + r + 1][nt * 16 + m16] = (ushortT)(p >> 16);
        }
    }
}

// pack one matrix entry into MFMA B-fragment order
__device__ __forceinline__ ushortT pack_one(const float* __restrict__ W, int u) {
    const int j = u & 7, lane = (u >> 3) & 63, f = u >> 9;  // u in [0,16384)
    const int nt = f & 7, ks = f >> 3;
    const int n = nt * 16 + (lane & 15);
    const int k = ks * 32 + (lane >> 4) * 8 + j;
    return f2bf(W[k * C + n]);
}

// ============================================================================
// prep1 (fused): pack Bpack (edge MLP, aw2 pre-scaled by log2e),
// pack Bpack2 (Wdst,Wsrc,Wlin,Win), pack BpackO (W_out),
// cvt pos->bf16 (float4 vectorized), hist of dst degrees. Block-role ranges.
// ============================================================================
extern "C" __global__ void __launch_bounds__(256)
prep1(const float* __restrict__ pw1, const float* __restrict__ pw2,
      const float* __restrict__ aw1, const float* __restrict__ aw2,
      const float* __restrict__ Wd,  const float* __restrict__ Wsrc,
      const float* __restrict__ Wl,  const float* __restrict__ Win,
      const float* __restrict__ Wout,
      const float* __restrict__ pos, ushortT* __restrict__ pos_bf,
      const int* __restrict__ ei, int* __restrict__ deg,
      ushortT* __restrict__ Bpack, ushortT* __restrict__ Bpack2,
      ushortT* __restrict__ BpackO, int N, int E)
{
    const int nb_cvt = (N * 32 + 255) / 256;
    const int b = blockIdx.x, tid = threadIdx.x;
    if (b < 256) {
        const int t = b * 256 + tid;
        const int s = t >> 14;
        const float* W = (s == 0) ? pw1 : (s == 1) ? pw2 : (s == 2) ? aw1 : aw2;
        const int u = t & 16383;
        const int j = u & 7, lane = (u >> 3) & 63, f = u >> 9;
        const int nt = f & 7, ks = f >> 3;
        const int n = nt * 16 + (lane & 15);
        const int k = ks * 32 + (lane >> 4) * 8 + j;
        float v = W[k * C + n];
        if (s == 3) v *= LOG2E;          // exp2 fold: attn layer-2 in log2 domain
        Bpack[t] = f2bf(v);
    } else if (b < 512) {
        const int t = (b - 256) * 256 + tid;
        const int s = t >> 14;
        const float* W = (s == 0) ? Wd : (s == 1) ? Wsrc : (s == 2) ? Wl : Win;
        Bpack2[t] = pack_one(W, t & 16383);
    } else if (b < 576) {
        const int t = (b - 512) * 256 + tid;     // [0, 16384)
        BpackO[t] = pack_one(Wout, t);
    } else if (b < 576 + nb_cvt) {
        const int i = (b - 576) * 256 + tid;
        if (i < N * 32) {
            const float4 v = ((const float4*)pos)[i];
            uint2 o; o.x = pk2(v.x, v.y); o.y = pk2(v.z, v.w);
            ((uint2*)pos_bf)[i] = o;
        }
    } else {
        const int e = (b - 576 - nb_cvt) * 256 + tid;
        if (e < E) atomicAdd(&deg[ei[E + e]], 1);
    }
}

extern "C" __global__ void __launch_bounds__(1024)
k_scan(const int* __restrict__ deg, int* __restrict__ off, int n)
{
    __shared__ int part[1024];
    const int t = threadIdx.x;
    const int chunk = (((n + 1023) / 1024) + 3) & ~3;      // multiple of 4
    const int lo = t * chunk, hi = min(lo + chunk, n);      // n%4==0 -> hi-lo %4==0
    int s = 0;
    for (int i = lo; i < hi; i += 4) {
        const int4 d4 = *(const int4*)(deg + i);
        s += d4.x + d4.y + d4.z + d4.w;
    }
    part[t] = s;
    __syncthreads();
    for (int d = 1; d < 1024; d <<= 1) {
        int v = (t >= d) ? part[t - d] : 0;
        __syncthreads();
        part[t] += v;
        __syncthreads();
    }
    int run = (t == 0) ? 0 : part[t - 1];
    for (int i = lo; i < hi; i += 4) {
        const int4 d4 = *(const int4*)(deg + i);
        int4 o;
        o.x = run;
        o.y = o.x + d4.x;
        o.z = o.y + d4.y;
        o.w = o.z + d4.z;
        *(int4*)(off + i) = o;
        run = o.w + d4.w;
    }
}

// ============================================================================
// prep2 (fused): node role (all-MFMA qkv + P = pos@pw1 hoist) + scatter role.
// ============================================================================
extern "C" __global__ void __launch_bounds__(256)
prep2(const float* __restrict__ x, const float* __restrict__ b_in,
      const ushortT* __restrict__ Bp2, const ushortT* __restrict__ Bpk,
      const float* __restrict__ pb1, const ushortT* __restrict__ pos_bf,
      ushortT* __restrict__ q_bf, ushortT* __restrict__ k_bf, ushortT* __restrict__ v_bf,
      ushortT* __restrict__ Pd_arr, ushortT* __restrict__ Ps_arr,
      const int* __restrict__ ei, const int* __restrict__ offp, int* __restrict__ curp,
      int* __restrict__ ss, int* __restrict__ sd, int N, int E, int nb_node)
{
    __shared__ ushortT xs[TILE][LDSW];   // 17.4 KB (ostage overlays this)
    __shared__ ushortT hs[TILE][LDSW];   // 17.4 KB
    const int b = blockIdx.x, tx = threadIdx.x;

    if (b >= nb_node) {
        // ---- scatter role ----
        const int e = (b - nb_node) * 256 + tx;
        if (e < E) {
            const int d = ei[E + e];
            const int p = offp[d] + atomicAdd(&curp[d], 1);
            ss[p] = ei[e];
            sd[p] = d;
        }
        return;
    }

    // ---- node role ----
    const int rg = tx >> 5;
    const int oc0 = (tx & 31) << 2;
    const int row0 = b * TILE;

    // stage x -> bf16 (wave-private rows)
#pragma unroll
    for (int j = 0; j < 8; ++j) {
        const int r = rg * 8 + j, n = row0 + r;
        float4 xv; xv.x = xv.y = xv.z = xv.w = 0.f;
        if (n < N) xv = *(const float4*)(x + (size_t)n * C + oc0);
        *(unsigned*)&xs[r][oc0]     = pk2(xv.x, xv.y);
        *(unsigned*)&xs[r][oc0 + 2] = pk2(xv.z, xv.w);
    }

    const int wv = tx >> 6, lane = tx & 63;
    const int quad = lane >> 4, m16 = lane & 15;
    const int row = lane >> 2, li = lane & 3;

    float binv[8];
#pragma unroll
    for (int nt = 0; nt < 8; ++nt) binv[nt] = b_in[nt * 16 + m16];

    const ushortT (*Ax)[LDSW] = (const ushortT (*)[LDSW])&xs[wv * 16];
    ushortT (*Ah)[LDSW] = (ushortT (*)[LDSW])&hs[wv * 16];

    floatx4 macc[8];
    // h = relu(x @ W_in + b_in)   (W_in in Bpack2 slot 3)
    wave_gemm(Ax, Bp2 + (size_t)3 * 16384, quad, m16, lane, macc);
    cstore_relu_r(Ah, macc, binv, quad, m16);

    __syncthreads();   // all xs reads done before ostage overlay is written

    ushortT (*OS)[LDSW] = (ushortT (*)[LDSW])&xs[wv * 16];   // ostage overlay
    ushortT* outs[3];
    outs[0] = q_bf; outs[1] = k_bf; outs[2] = v_bf;

    const int nrow = row0 + wv * 16 + row;

#pragma unroll 1
    for (int m = 0; m < 3; ++m) {
        wave_gemm((const ushortT (*)[LDSW])Ah, Bp2 + (size_t)m * 16384, quad, m16, lane, macc);
#pragma unroll
        for (int nt = 0; nt < 8; ++nt) {
#pragma unroll
            for (int r = 0; r < 4; r += 2) {
                const unsigned p = pk2(macc[nt][r], macc[nt][r + 1]);
                OS[quad * 4 + r][nt * 16 + m16]     = (ushortT)(p & 0xffffu);
                OS[quad * 4 + r + 1][nt * 16 + m16] = (ushortT)(p >> 16);
            }
        }
        if (nrow < N) {
#pragma unroll
            for (int i = 0; i < 4; ++i) {
                const ushort8 v8 = *(const ushort8*)&OS[row][i * 32 + li * 8];
                *(ushort8*)(outs[m] + (size_t)nrow * C + i * 32 + li * 8) = v8;
            }
        }
    }

    // ---- P = pos @ pw1 (hoisted pos_nn layer-1 GEMM) ----
    __syncthreads();   // hs reads (gemms) + OS reads (stores) all complete
    {
        const ushortT* srcp = pos_bf + (size_t)min(nrow, N - 1) * C;
#pragma unroll
        for (int i = 0; i < 4; ++i) {
            const ushort8 v8 = *(const ushort8*)(srcp + i * 32 + li * 8);
            *(ushort8*)&hs[wv * 16 + row][i * 32 + li * 8] = v8;
        }
    }
    __syncthreads();
    wave_gemm((const ushortT (*)[LDSW])Ah, Bpk /*slot 0 = pw1*/, quad, m16, lane, macc);

    float b1v[8];
#pragma unroll
    for (int nt = 0; nt < 8; ++nt) b1v[nt] = pb1[nt * 16 + m16];

    // pass 1: Pd = P + b1
#pragma unroll
    for (int nt = 0; nt < 8; ++nt) {
#pragma unroll
        for (int r = 0; r < 4; r += 2) {
            const unsigned p = pk2(macc[nt][r] + b1v[nt], macc[nt][r + 1] + b1v[nt]);
            OS[quad * 4 + r][nt * 16 + m16]     = (ushortT)(p & 0xffffu);
            OS[quad * 4 + r + 1][nt * 16 + m16] = (ushortT)(p >> 16);
        }
    }
    if (nrow < N) {
#pragma unroll
        for (int i = 0; i < 4; ++i) {
            const ushort8 v8 = *(const ushort8*)&OS[row][i * 32 + li * 8];
            *(ushort8*)(Pd_arr + (size_t)nrow * C + i * 32 + li * 8) = v8;
        }
    }
    __syncthreads();
    // pass 2: Ps = P
#pragma unroll
    for (int nt = 0; nt < 8; ++nt) {
#pragma unroll
        for (int r = 0; r < 4; r += 2) {
            const unsigned p = pk2(macc[nt][r], macc[nt][r + 1]);
            OS[quad * 4 + r][nt * 16 + m16]     = (ushortT)(p & 0xffffu);
            OS[quad * 4 + r + 1][nt * 16 + m16] = (ushortT)(p >> 16);
        }
    }
    if (nrow < N) {
#pragma unroll
        for (int i = 0; i < 4; ++i) {
            const ushort8 v8 = *(const ushort8*)&OS[row][i * 32 + li * 8];
            *(ushort8*)(Ps_arr + (size_t)nrow * C + i * 32 + li * 8) = v8;
        }
    }
}

// ============================================================================
// kernel 2 (MFMA): edges SORTED BY DST; segmented-scan epilogue (direct
// atomics — r10-proven). This round: 1-tile DATA prefetch of Pd/Ps/Vv (the
// immediately-consumed gathers); Qv/Kv stay loop-top (covered by A1+gemm1).
// Index pipeline is 2 tiles deep so data prefetch never waits on indices.
// ============================================================================
__device__ __forceinline__ void gather4(const ushortT* __restrict__ base, int node, int li,
                                        ushort8 dst[4])
{
    const ushort8* p = (const ushort8*)(base + (size_t)node * C) + li;
    dst[0] = p[0]; dst[1] = p[4]; dst[2] = p[8]; dst[3] = p[12];   // chunk i at ushort8 index i*4+li
}

extern "C" __global__ void __launch_bounds__(ETHREADS)
edge_mfma(const ushortT* __restrict__ Pd_arr, const ushortT* __restrict__ Ps_arr,
          const int* __restrict__ ss, const int* __restrict__ sd,
          const ushortT* __restrict__ q_bf, const ushortT* __restrict__ k_bf,
          const ushortT* __restrict__ v_bf, const ushortT* __restrict__ Bpack,
          const float* __restrict__ pb2,
          const float* __restrict__ ab1, const float* __restrict__ ab2,
          float* __restrict__ z, float* __restrict__ aggU, int E)
{
    __shared__ ushortT Aslab[EWPB][EPW][LDSW];   // 8.7 KB
    __shared__ ushortT Vslab[EWPB][EPW][LDSW];   // 8.7 KB
    __shared__ int     Dslab[EWPB][EPW];         // 128 B
    const int tid = threadIdx.x;
    const int wv = tid >> 6, lane = tid & 63;
    const int quad = lane >> 4, m16 = lane & 15;
    const int row = lane >> 2, li = lane & 3;      // line-coherent staging mapping
    ushortT (*A)[LDSW] = Aslab[wv];
    ushortT (*V)[LDSW] = Vslab[wv];

    float pb2v[8], ab1v[8], ab2v[8];
#pragma unroll
    for (int nt = 0; nt < 8; ++nt) {
        pb2v[nt] = pb2[nt * 16 + m16];
        ab1v[nt] = ab1[nt * 16 + m16];
        ab2v[nt] = ab2[nt * 16 + m16] * LOG2E;     // log2-domain bias
    }

    const ushortT* B1 = Bpack + 16384;
    const ushortT* B2 = Bpack + 32768;
    const ushortT* B3 = Bpack + 49152;

    const int wave_base = (blockIdx.x * EWPB + wv) * (GTILES * EPW);

    const int c2 = lane * 2;
    int   cur_dst = -1;
    float zs0 = 0.f, zs1 = 0.f, gs0 = 0.f, gs1 = 0.f;

    // ---- pipeline state ----
    // tile t:  esC/edC (gather nodes), sdrC (scan dsts), PdP/PsP/VvP (data)
    // tile t+1: esN/edN/sdrN (indices, prefetched)
    int esC, edC, sdrC[4];
    int esN, edN, sdrN[4];
    ushort8 PdP[4], PsP[4], VvP[4];
    {
        const int eidx = min(wave_base + row, E - 1);
        esC = ss[eidx]; edC = sd[eidx];
#pragma unroll
        for (int r = 0; r < 4; ++r)
            sdrC[r] = sd[min(wave_base + quad * 4 + r, E - 1)];
        gather4(Pd_arr, edC, li, PdP);
        gather4(Ps_arr, esC, li, PsP);
        gather4(v_bf,  esC, li, VvP);
        const int e2 = wave_base + EPW;
        const int ei2 = min(e2 + row, E - 1);
        esN = ss[ei2]; edN = sd[ei2];
#pragma unroll
        for (int r = 0; r < 4; ++r)
            sdrN[r] = sd[min(e2 + quad * 4 + r, E - 1)];
    }

#pragma unroll 1
    for (int t = 0; t < GTILES; ++t) {
        const int e_base = wave_base + t * EPW;
        if (m16 == 0) {
#pragma unroll
            for (int r = 0; r < 4; ++r) Dslab[wv][quad * 4 + r] = sdrC[r];
        }

        // Qv/Kv: loop-top load, consumed at A2 (covered by A1 + gemm1)
        ushort8 Qv[4], Kv[4];
        gather4(q_bf, edC, li, Qv);
        gather4(k_bf, esC, li, Kv);

        // ---- A1 = relu(Pd[dst] - Ps[src]) from PREFETCHED data; stage v ----
#pragma unroll
        for (int i = 0; i < 4; ++i) {
            const uintx4 pd = *(const uintx4*)&PdP[i];
            const uintx4 ps = *(const uintx4*)&PsP[i];
            uintx4 o;
#pragma unroll
            for (int w = 0; w < 4; ++w) {
                const float2 a = upk2(pd[w]), b = upk2(ps[w]);
                o[w] = pk2(fmaxf(a.x - b.x, 0.f), fmaxf(a.y - b.y, 0.f));
            }
            *(uintx4*)&A[row][i * 32 + li * 8] = o;
            *(ushort8*)&V[row][i * 32 + li * 8] = VvP[i];
        }

        floatx4 acc[8];

        // ---- pos_nn layer 2 -> delta (packed regs + slab) ----
        wave_gemm(A, B1, quad, m16, lane, acc);
        unsigned dlp[8][2];
#pragma unroll
        for (int nt = 0; nt < 8; ++nt) {
            const float b = pb2v[nt];
            const unsigned p0 = pk2(fmaxf(acc[nt][0] + b, 0.f), fmaxf(acc[nt][1] + b, 0.f));
            const unsigned p1 = pk2(fmaxf(acc[nt][2] + b, 0.f), fmaxf(acc[nt][3] + b, 0.f));
            dlp[nt][0] = p0; dlp[nt][1] = p1;
            A[quad * 4 + 0][nt * 16 + m16] = (ushortT)(p0 & 0xffffu);
            A[quad * 4 + 1][nt * 16 + m16] = (ushortT)(p0 >> 16);
            A[quad * 4 + 2][nt * 16 + m16] = (ushortT)(p1 & 0xffffu);
            A[quad * 4 + 3][nt * 16 + m16] = (ushortT)(p1 >> 16);
        }

        // ---- A2 = bf16( q[dst] - k[src] + delta ) ----
#pragma unroll
        for (int i = 0; i < 4; ++i) {
            const uintx4 dv = *(const uintx4*)&A[row][i * 32 + li * 8];
            const uintx4 qv = *(const uintx4*)&Qv[i];
            const uintx4 kv = *(const uintx4*)&Kv[i];
            uintx4 o;
#pragma unroll
            for (int w = 0; w < 4; ++w) {
                const float2 qq = upk2(qv[w]), kk = upk2(kv[w]), dd = upk2(dv[w]);
                o[w] = pk2(qq.x - kk.x + dd.x, qq.y - kk.y + dd.y);
            }
            *(uintx4*)&A[row][i * 32 + li * 8] = o;
        }

        // ---- DATA prefetch for tile t+1 (indices already resident) ----
        ushort8 PdN[4], PsN[4], VvN[4];
        if (t + 1 < GTILES) {
            gather4(Pd_arr, edN, li, PdN);
            gather4(Ps_arr, esN, li, PsN);
            gather4(v_bf,  esN, li, VvN);
        }
        // ---- index prefetch for tile t+2 ----
        int esN2 = esN, edN2 = edN, nsdr2[4];
#pragma unroll
        for (int r = 0; r < 4; ++r) nsdr2[r] = sdrN[r];
        if (t + 2 < GTILES) {
            const int e2 = e_base + 2 * EPW;
            const int ei2 = min(e2 + row, E - 1);
            esN2 = ss[ei2]; edN2 = sd[ei2];
#pragma unroll
            for (int r = 0; r < 4; ++r)
                nsdr2[r] = sd[min(e2 + quad * 4 + r, E - 1)];
        }

        // ---- attn_nn layer 1 ----
        wave_gemm(A, B2, quad, m16, lane, acc);
        cstore_relu_r(A, acc, ab1v, quad, m16);

        // ---- attn_nn layer 2 (log2 domain) -> ea = exp2(relu(alpha'+b')) ----
        wave_gemm(A, B3, quad, m16, lane, acc);
#pragma unroll
        for (int nt = 0; nt < 8; ++nt) {
            const float b = ab2v[nt];
#pragma unroll
            for (int r = 0; r < 4; ++r)
                acc[nt][r] = exp2_hw(fmaxf(acc[nt][r] + b, 0.f));  // == exp(relu(alpha))
        }

        // ---- zero ea for out-of-range (clamped duplicate) edges ----
        if (e_base + EPW > E) {
#pragma unroll
            for (int r = 0; r < 4; ++r)
                if (e_base + quad * 4 + r >= E) {
#pragma unroll
                    for (int nt = 0; nt < 8; ++nt) acc[nt][r] = 0.f;
                }
        }

        // ---- transpose: A <- ea (bf16), V <- v+delta (bf16), edge-major ----
#pragma unroll
        for (int nt = 0; nt < 8; ++nt) {
#pragma unroll
            for (int r = 0; r < 4; ++r) {
                const float2 dpair = upk2(dlp[nt][r >> 1]);
                const float dlv = (r & 1) ? dpair.y : dpair.x;
                const int ridx = quad * 4 + r, cidx = nt * 16 + m16;
                const float vv = bf2f(V[ridx][cidx]);
                V[ridx][cidx] = f2bf(vv + dlv);
                A[ridx][cidx] = f2bf(acc[nt][r]);
            }
        }

        // ---- per-lane segmented scan over the 16 sorted edges ----
#pragma unroll 4
        for (int e = 0; e < EPW; ++e) {
            const int d = Dslab[wv][e];
            const float2 ea2 = upk2(*(const unsigned*)&A[e][c2]);
            const float2 vp2 = upk2(*(const unsigned*)&V[e][c2]);
            if (d != cur_dst) {
                if (cur_dst >= 0) {
                    float* zp = z    + (size_t)cur_dst * C + c2;
                    float* gp = aggU + (size_t)cur_dst * C + c2;
                    atomic_add_f32(zp,     zs0);
                    atomic_add_f32(zp + 1, zs1);
                    atomic_add_f32(gp,     gs0);
                    atomic_add_f32(gp + 1, gs1);
                }
                cur_dst = d;
                zs0 = ea2.x;           zs1 = ea2.y;
                gs0 = ea2.x * vp2.x;   gs1 = ea2.y * vp2.y;
            } else {
                zs0 += ea2.x;                   zs1 += ea2.y;
                gs0 = fmaf(ea2.x, vp2.x, gs0);  gs1 = fmaf(ea2.y, vp2.y, gs1);
            }
        }

        // ---- rotate pipeline state ----
        esC = esN; edC = edN;
#pragma unroll
        for (int r = 0; r < 4; ++r) sdrC[r] = sdrN[r];
        esN = esN2; edN = edN2;
#pragma unroll
        for (int r = 0; r < 4; ++r) sdrN[r] = nsdr2[r];
#pragma unroll
        for (int i = 0; i < 4; ++i) { PdP[i] = PdN[i]; PsP[i] = PsN[i]; VvP[i] = VvN[i]; }
    }

    // ---- final flush ----
    if (cur_dst >= 0) {
        float* zp = z    + (size_t)cur_dst * C + c2;
        float* gp = aggU + (size_t)cur_dst * C + c2;
        atomic_add_f32(zp,     zs0);
        atomic_add_f32(zp + 1, zs1);
        atomic_add_f32(gp,     gs0);
        atomic_add_f32(gp + 1, gs1);
    }
}

// ============================================================================
// kernel 3 (MFMA): out = relu( bf16(aggU/(z+1e-16)) @ W_out + b_out )
// ============================================================================
extern "C" __global__ void __launch_bounds__(THREADS)
out_kernel(const float* __restrict__ aggU, const float* __restrict__ z,
           const ushortT* __restrict__ BpO, const float* __restrict__ b_out,
           float* __restrict__ out, int N)
{
    __shared__ ushortT us[TILE][LDSW];   // 17.4 KB
    const int tx = threadIdx.x;
    const int rg = tx >> 5;
    const int oc0 = (tx & 31) << 2;
    const int row0 = blockIdx.x * TILE;

#pragma unroll
    for (int j = 0; j < 8; ++j) {
        const int r = rg * 8 + j, n = row0 + r;
        float4 a; a.x = a.y = a.z = a.w = 0.f;
        if (n < N) {
            const float4 g  = *(const float4*)(aggU + (size_t)n * C + oc0);
            const float4 zz = *(const float4*)(z    + (size_t)n * C + oc0);
            a.x = g.x / (zz.x + 1e-16f);
            a.y = g.y / (zz.y + 1e-16f);
            a.z = g.z / (zz.z + 1e-16f);
            a.w = g.w / (zz.w + 1e-16f);
        }
        *(unsigned*)&us[r][oc0]     = pk2(a.x, a.y);
        *(unsigned*)&us[r][oc0 + 2] = pk2(a.z, a.w);
    }
    // rows rg*8+j are wave-private (rg in {2wv,2wv+1}) -> no barrier

    const int wv = tx >> 6, lane = tx & 63;
    const int quad = lane >> 4, m16 = lane & 15;

    floatx4 macc[8];
    wave_gemm((const ushortT (*)[LDSW])&us[wv * 16], BpO, quad, m16, lane, macc);

    float bo[8];
#pragma unroll
    for (int nt = 0; nt < 8; ++nt) bo[nt] = b_out[nt * 16 + m16];

#pragma unroll
    for (int r = 0; r < 4; ++r) {
        const int n = row0 + wv * 16 + quad * 4 + r;
        if (n < N) {
            float* op = out + (size_t)n * C + m16;
#pragma unroll
            for (int nt = 0; nt < 8; ++nt)
                op[nt * 16] = fmaxf(macc[nt][r] + bo[nt], 0.f);
        }
    }
}

// ---------------------------------------------------------------------------
extern "C" void kernel_launch(void* const* d_in, const int* in_sizes, int n_in,
                              void* d_out, int out_size, void* d_ws, size_t ws_size,
                              hipStream_t stream)
{
    const float* x     = (const float*)d_in[0];
    const float* pos   = (const float*)d_in[1];
    const int*   ei    = (const int*)  d_in[2];
    const float* W_in  = (const float*)d_in[3];
    const float* b_in  = (const float*)d_in[4];
    const float* W_lin = (const float*)d_in[5];
    const float* W_src = (const float*)d_in[6];
    const float* W_dst = (const float*)d_in[7];
    const float* pw1   = (const float*)d_in[8];
    const float* pb1   = (const float*)d_in[9];
    const float* pw2   = (const float*)d_in[10];
    const float* pb2   = (const float*)d_in[11];
    const float* aw1   = (const float*)d_in[12];
    const float* ab1   = (const float*)d_in[13];
    const float* aw2   = (const float*)d_in[14];
    const float* ab2   = (const float*)d_in[15];
    const float* W_out = (const float*)d_in[16];
    const float* b_out = (const float*)d_in[17];

    const int N = in_sizes[0] / C;
    const int E = in_sizes[2] / 2;
    const size_t NC = (size_t)N * C;

    // workspace layout — ALL gathered bf16 arrays 256-B aligned:
    //   z | aggU | q | k | v | Pd | Ps | pos_bf | Bpack | Bpack2 | BpackO |
    //   deg | cur | off | ss | sd
    float*   z      = (float*)d_ws;                          // [N,C] fp32
    float*   aggU   = z + NC;                                // [N,C] fp32
    ushortT* q_bf   = (ushortT*)(aggU + NC);                 // [N,C] bf16 (256B-aligned)
    ushortT* k_bf   = q_bf + NC;
    ushortT* v_bf   = k_bf + NC;
    ushortT* Pd_arr = v_bf + NC;                             // [N,C] bf16: pos@pw1 + pb1
    ushortT* Ps_arr = Pd_arr + NC;                           // [N,C] bf16: pos@pw1
    ushortT* pos_bf = Ps_arr + NC;
    ushortT* Bpack  = pos_bf + NC;                           // 65536 bf16 (edge MLP weights)
    ushortT* Bpack2 = Bpack + 65536;                         // 65536 bf16 (Wdst,Wsrc,Wlin,Win)
    ushortT* BpackO = Bpack2 + 65536;                        // 16384 bf16 (W_out)
    int*     deg    = (int*)(BpackO + 16384);                // [N]
    int*     curp   = deg + N;                               // [N]
    int*     offp   = curp + N;                              // [N]
    int*     ss     = offp + N;                              // [E] sorted src
    int*     sdst   = ss + E;                                // [E] sorted dst

    hipMemsetAsync(z, 0, 2 * NC * sizeof(float), stream);
    hipMemsetAsync(deg, 0, 2 * (size_t)N * sizeof(int), stream);  // deg + cur

    const int nb_cvt  = (N * 32 + 255) / 256;
    const int nb_hist = (E + 255) / 256;
    prep1<<<576 + nb_cvt + nb_hist, 256, 0, stream>>>(pw1, pw2, aw1, aw2,
                                                      W_dst, W_src, W_lin, W_in, W_out,
                                                      pos, pos_bf, ei, deg,
                                                      Bpack, Bpack2, BpackO, N, E);

    k_scan<<<1, 1024, 0, stream>>>(deg, offp, N);

    const int nb = (N + TILE - 1) / TILE;
    prep2<<<nb + nb_hist, 256, 0, stream>>>(x, b_in, Bpack2, Bpack, pb1, pos_bf,
                                            q_bf, k_bf, v_bf, Pd_arr, Ps_arr,
                                            ei, offp, curp, ss, sdst, N, E, nb);

    const int edges_per_block = EWPB * GTILES * EPW;         // 256
    const int eb = (E + edges_per_block - 1) / edges_per_block;
    edge_mfma<<<eb, ETHREADS, 0, stream>>>(Pd_arr, Ps_arr, ss, sdst, q_bf, k_bf, v_bf, Bpack,
                                           pb2, ab1, ab2, z, aggU, E);
    out_kernel<<<nb, THREADS, 0, stream>>>(aggU, z, BpackO, b_out, (float*)d_out, N);
}